// Round 1
// baseline (4768.779 us; speedup 1.0000x reference)
//
#include <hip/hip_runtime.h>
#include <hip/hip_bf16.h>

#define DEV __device__ __forceinline__

namespace {
constexpr int T_ = 16;
constexpr int C_ = 64;
constexpr int H_ = 128;
constexpr int W_ = 128;
constexpr int HW_ = H_ * W_;            // 16384
constexpr long CHW_ = (long)C_ * HW_;   // 1,048,576 floats per (n,t) plane
}

struct Bil { int o00, o01, o10, o11; float w00, w01, w10, w11; };

DEV Bil make_bil(float gx, float gy) {
  float x0f = floorf(gx), y0f = floorf(gy);
  float wx = gx - x0f, wy = gy - y0f;
  int x0 = (int)x0f, y0 = (int)y0f;
  int x1 = x0 + 1, y1 = y0 + 1;
  bool vx0 = (x0 >= 0) && (x0 < W_), vx1 = (x1 >= 0) && (x1 < W_);
  bool vy0 = (y0 >= 0) && (y0 < H_), vy1 = (y1 >= 0) && (y1 < H_);
  int cx0 = min(max(x0, 0), W_ - 1), cx1 = min(max(x1, 0), W_ - 1);
  int cy0 = min(max(y0, 0), H_ - 1), cy1 = min(max(y1, 0), H_ - 1);
  Bil b;
  b.o00 = cy0 * W_ + cx0; b.o01 = cy0 * W_ + cx1;
  b.o10 = cy1 * W_ + cx0; b.o11 = cy1 * W_ + cx1;
  b.w00 = (vx0 && vy0) ? (1.f - wx) * (1.f - wy) : 0.f;
  b.w01 = (vx1 && vy0) ? wx * (1.f - wy) : 0.f;
  b.w10 = (vx0 && vy1) ? (1.f - wx) * wy : 0.f;
  b.w11 = (vx1 && vy1) ? wx * wy : 0.f;
  return b;
}

// Kernel 1: flow-warp (a2, a1) + concat x + 1x1 conv (192->64), all fp32.
// grid = 256 blocks x 256 threads; thread = (n, co-half, pixel).
// (UNCHANGED this round — conv3_k is the dominant cost.)
__global__ __launch_bounds__(256) void warp_fc_k(
    const float* __restrict__ flows,    // (N,T,2,HW)
    const float* __restrict__ xfeats,   // pristine feats base (x_t source)
    const float* __restrict__ y1p, long y1s,   // y1 planes, n-stride (floats)
    const float* __restrict__ y2p, long y2s,   // y2 planes
    const float* __restrict__ Wfc, const float* __restrict__ bfc,
    int f1t, int f2t, int t,
    float* __restrict__ ifp, long ifs) {       // infeat out, n-stride
  __shared__ float wl[192 * 64];   // k-major: wl[k*64+co]
  const int tid = threadIdx.x;
  for (int i = tid; i < 192 * 64; i += 256) {
    int k = i >> 6, co = i & 63;
    wl[i] = Wfc[co * 192 + k];
  }
  __syncthreads();

  const int n    = blockIdx.x >> 7;          // 0..1
  const int half = (blockIdx.x >> 6) & 1;    // co-half 0..1
  const int p    = ((blockIdx.x & 63) << 8) + tid;   // 0..16383
  const int py = p >> 7, px = p & (W_ - 1);

  float f1x = 0.f, f1y = 0.f;
  if (f1t >= 0) {
    const float* fp = flows + (long)((n * T_ + f1t) * 2) * HW_;
    f1x = fp[p];
    f1y = fp[HW_ + p];
  }
  Bil b1 = make_bil((float)px + f1x, (float)py + f1y);

  float f2cx = f1x, f2cy = f1y;   // warp of zero field is zero
  if (f2t >= 0) {
    const float* f2p = flows + (long)((n * T_ + f2t) * 2) * HW_;
    f2cx += b1.w00 * f2p[b1.o00] + b1.w01 * f2p[b1.o01] +
            b1.w10 * f2p[b1.o10] + b1.w11 * f2p[b1.o11];
    const float* f2q = f2p + HW_;
    f2cy += b1.w00 * f2q[b1.o00] + b1.w01 * f2q[b1.o01] +
            b1.w10 * f2q[b1.o10] + b1.w11 * f2q[b1.o11];
  }
  Bil b2 = make_bil((float)px + f2cx, (float)py + f2cy);

  float acc[32];
  #pragma unroll
  for (int i = 0; i < 32; i++) acc[i] = bfc[half * 32 + i];

  // k = 0..63 : a2 = warp(y2, f2c)
  const float* y2b = y2p + (long)n * y2s;
  for (int c0 = 0; c0 < 64; c0++) {
    const float* pl = y2b + (long)c0 * HW_;
    float v = b2.w00 * pl[b2.o00] + b2.w01 * pl[b2.o01] +
              b2.w10 * pl[b2.o10] + b2.w11 * pl[b2.o11];
    const float* wr = wl + c0 * 64 + half * 32;
    #pragma unroll
    for (int i = 0; i < 32; i++) acc[i] += wr[i] * v;
  }
  // k = 64..127 : a1 = warp(y1, f1)
  const float* y1b = y1p + (long)n * y1s;
  for (int c0 = 0; c0 < 64; c0++) {
    const float* pl = y1b + (long)c0 * HW_;
    float v = b1.w00 * pl[b1.o00] + b1.w01 * pl[b1.o01] +
              b1.w10 * pl[b1.o10] + b1.w11 * pl[b1.o11];
    const float* wr = wl + (64 + c0) * 64 + half * 32;
    #pragma unroll
    for (int i = 0; i < 32; i++) acc[i] += wr[i] * v;
  }
  // k = 128..191 : x = feats[:, t]
  const float* xb = xfeats + (long)(n * T_ + t) * CHW_ + p;
  for (int c0 = 0; c0 < 64; c0++) {
    float v = xb[(long)c0 * HW_];
    const float* wr = wl + (128 + c0) * 64 + half * 32;
    #pragma unroll
    for (int i = 0; i < 32; i++) acc[i] += wr[i] * v;
  }

  float* o = ifp + (long)n * ifs + p;
  #pragma unroll
  for (int i = 0; i < 32; i++) o[(long)(half * 32 + i) * HW_] = acc[i];
}

// 3x3 SAME conv 64->64, fp32. REWRITE (v2):
//   Old version was LDS-issue + bank-conflict bound (36x ds_read_b32 per ci
//   for 144 FMA; SQ_LDS_BANK_CONFLICT 1.29e7; VALUBusy 29%).
//   New mapping: block = 16x16 px tile x 16 co (cog 0..3); 256 threads =
//   32 patches (8 prr x 4 pcc, each 2 rows x 4 cols) x 8 colanes; each thread
//   computes TWO co (colane, colane+8) -> 144 FMA per 8 ds_read_b128.
//   Tile row stride 24 floats: prr row-offsets 0/48 mod 32 -> the two prr
//   groups in a wave hit disjoint bank ranges (conflict-free b128 reads),
//   and all b128 addresses stay 16B-aligned (96B row stride, pcc*16B col).
//   4 ci planes staged per round -> 32 barriers instead of 128.
// MODE 0: +bias1, leaky_relu.  MODE 1: +bias2 +x residual.
template <int MODE>
__global__ __launch_bounds__(256) void conv3_k(
    const float* __restrict__ in, long ins,       // input planes, n-stride
    const float* __restrict__ Wt,                 // (64,64,3,3)
    const float* __restrict__ bias,
    const float* __restrict__ xfeats, int t,      // residual source (MODE 1)
    float* __restrict__ outf, long outs) {        // fp32 out planes, n-stride
  constexpr int TS = 24;        // padded tile row stride (floats)
  constexpr int CI_STEP = 4;    // ci planes staged per barrier round
  __shared__ float tile[CI_STEP][18][TS];

  const int tilex = blockIdx.x, tiley = blockIdx.y;
  const int n = blockIdx.z >> 2, cog = blockIdx.z & 3;
  const int tid = threadIdx.x;
  const int colane = tid & 7;        // 0..7
  const int patch  = tid >> 3;       // 0..31
  const int prr = patch >> 2;        // 0..7  (2-row strips)
  const int pcc = patch & 3;         // 0..3  (4-col strips)
  const int co0 = cog * 16 + colane; // thread's channels: co0 and co0+8

  float acc[2][2][4];
  #pragma unroll
  for (int q = 0; q < 2; q++)
    #pragma unroll
    for (int i = 0; i < 2; i++)
      #pragma unroll
      for (int j = 0; j < 4; j++) acc[q][i][j] = 0.f;

  const float* inn = in + (long)n * ins;
  const int gy0 = tiley * 16 - 1, gx0 = tilex * 16 - 1;

  for (int cb = 0; cb < 64; cb += CI_STEP) {
    // ---- stage CI_STEP input planes (18x18 valid, zero-padded edges) ----
    for (int cc = 0; cc < CI_STEP; cc++) {
      const float* ip = inn + (long)(cb + cc) * HW_;
      for (int i = tid; i < 324; i += 256) {
        int r = i / 18, c = i - r * 18;
        int gy = gy0 + r, gx = gx0 + c;
        float v = 0.f;
        if (gy >= 0 && gy < H_ && gx >= 0 && gx < W_) v = ip[gy * W_ + gx];
        tile[cc][r][c] = v;
      }
    }
    __syncthreads();

    for (int cc = 0; cc < CI_STEP; cc++) {
      const int ci = cb + cc;
      // weights for both co (L1-cached; 8 lanes/wave share each address)
      float w0[9], w1[9];
      const float* wp0 = Wt + ((long)co0 * 64 + ci) * 9;
      const float* wp1 = Wt + ((long)(co0 + 8) * 64 + ci) * 9;
      #pragma unroll
      for (int j = 0; j < 9; j++) { w0[j] = wp0[j]; w1[j] = wp1[j]; }

      // input registers: 4 rows x 8 cols via 2x ds_read_b128 per row
      // (cols pcc*4+6..7 may be unstaged garbage for pcc==3 — never used)
      float vv[4][8];
      #pragma unroll
      for (int r = 0; r < 4; r++) {
        const float* tp = &tile[cc][prr * 2 + r][pcc * 4];
        float4 a = *reinterpret_cast<const float4*>(tp);
        float4 b = *reinterpret_cast<const float4*>(tp + 4);
        vv[r][0] = a.x; vv[r][1] = a.y; vv[r][2] = a.z; vv[r][3] = a.w;
        vv[r][4] = b.x; vv[r][5] = b.y; vv[r][6] = b.z; vv[r][7] = b.w;
      }

      // 2 co x 2 oy x 4 ox x 9 taps = 288 FMA per ci
      // (per-output order ci -> ky -> kx identical to v1: bit-identical sums)
      #pragma unroll
      for (int oy = 0; oy < 2; oy++)
        #pragma unroll
        for (int ky = 0; ky < 3; ky++)
          #pragma unroll
          for (int kx = 0; kx < 3; kx++)
            #pragma unroll
            for (int ox = 0; ox < 4; ox++) {
              float x = vv[oy + ky][ox + kx];
              acc[0][oy][ox] += w0[ky * 3 + kx] * x;
              acc[1][oy][ox] += w1[ky * 3 + kx] * x;
            }
    }
    __syncthreads();
  }

  // ---- epilogue: bias (+leaky | +residual), float4 stores ----
  const int py0 = tiley * 16 + prr * 2, px0 = tilex * 16 + pcc * 4;
  #pragma unroll
  for (int q = 0; q < 2; q++) {
    const int co = co0 + q * 8;
    const float bs = bias[co];
    float* ob = outf + (long)n * outs + (long)co * HW_;
    const float* xb = (MODE == 1)
        ? xfeats + (long)(n * T_ + t) * CHW_ + (long)co * HW_ : nullptr;
    #pragma unroll
    for (int oy = 0; oy < 2; oy++) {
      const long p = (long)(py0 + oy) * W_ + px0;
      float4 r;
      r.x = acc[q][oy][0] + bs;
      r.y = acc[q][oy][1] + bs;
      r.z = acc[q][oy][2] + bs;
      r.w = acc[q][oy][3] + bs;
      if (MODE == 0) {
        r.x = (r.x > 0.f) ? r.x : 0.1f * r.x;
        r.y = (r.y > 0.f) ? r.y : 0.1f * r.y;
        r.z = (r.z > 0.f) ? r.z : 0.1f * r.z;
        r.w = (r.w > 0.f) ? r.w : 0.1f * r.w;
      } else {
        float4 xres = *reinterpret_cast<const float4*>(&xb[p]);
        r.x += xres.x; r.y += xres.y; r.z += xres.z; r.w += xres.w;
      }
      *reinterpret_cast<float4*>(&ob[p]) = r;
    }
  }
}

extern "C" void kernel_launch(void* const* d_in, const int* in_sizes, int n_in,
                              void* d_out, int out_size, void* d_ws, size_t ws_size,
                              hipStream_t stream) {
  // Inputs fp32 AND output fp32 (reference returns jnp.float32; the test's
  // "(bf16, ...)" label is a hardcoded string). Rounds 4-6's bit-identical
  // absmax across different pipelines is explained by bf16-written output
  // being read back as fp32.
  //
  // d_out planes (n,t) are the exact fp32 recurrent state: written at step t,
  // read as y1/y2 at steps t+1/t+2 (feats plane 0 for t<2). Scratch (infeat,
  // h1) -> d_ws if >=16 MiB, else dead feats/d_out planes (restore-per-launch
  // semantics make feats planes reusable once consumed).
  float* fmut = (float*)d_in[0];              // feats (2,16,64,128,128)
  const float* flows = (const float*)d_in[1]; // (2,16,2,128,128)
  const float* Wfc   = (const float*)d_in[2]; // (64,192)
  const float* bfc   = (const float*)d_in[3];
  const float* W1    = (const float*)d_in[4]; // (64,64,3,3)
  const float* b1v   = (const float*)d_in[5];
  const float* W2    = (const float*)d_in[6];
  const float* b2v   = (const float*)d_in[7];
  float* outF = (float*)d_out;                // (2,16,64,128,128) fp32

  const long FS = (long)T_ * CHW_;            // n-stride of feats/out (floats)
  float* ws = (float*)d_ws;
  const bool use_ws = ws_size >= (size_t)4 * CHW_ * sizeof(float);  // 16 MiB

  dim3 g3(8, 8, 8);
  for (int t = 0; t < T_; t++) {
    // ---- state sources (n-stride FS for both feats and out) ----
    const float* y1p = (t >= 1) ? outF + (long)(t - 1) * CHW_ : fmut;
    const float* y2p = (t >= 2) ? outF + (long)(t - 2) * CHW_ : fmut;

    // ---- scratch: infeat and h1 ----
    float *ifp, *h1p;
    long ifs, h1s;
    if (use_ws) {
      ifp = ws;                 ifs = CHW_;   // (N,C,H,W), 8 MiB
      h1p = ws + 2 * CHW_;      h1s = CHW_;   // 8 MiB
    } else {
      if (t == 0)      { ifp = outF + (long)14 * CHW_; ifs = FS; }
      else if (t == 1) { ifp = outF + (long)15 * CHW_; ifs = FS; }
      else             { ifp = fmut + (long)(t - 1) * CHW_; ifs = FS; }
      if (t == 0)      { h1p = outF + (long)15 * CHW_; h1s = FS; }
      else             { h1p = fmut; h1s = FS; }   // feats plane 0, dead for t>=1
    }

    warp_fc_k<<<256, 256, 0, stream>>>(
        flows, fmut, y1p, FS, y2p, FS, Wfc, bfc, t - 1, t - 2, t, ifp, ifs);
    conv3_k<0><<<g3, 256, 0, stream>>>(ifp, ifs, W1, b1v, nullptr, 0, h1p, h1s);
    conv3_k<1><<<g3, 256, 0, stream>>>(h1p, h1s, W2, b2v, fmut, t,
                                       outF + (long)t * CHW_, FS);
  }
}